// Round 3
// baseline (657.237 us; speedup 1.0000x reference)
//
#include <hip/hip_runtime.h>
#include <cstdint>
#include <cstddef>

#define RR 32
#define R3 32768
#define NPT 32768
#define CH 240
#define CH2 480
#define NB 4
#define Y_ELEMS 31457280   // 4*240*32768

typedef __attribute__((ext_vector_type(8))) short short8v;
typedef __attribute__((ext_vector_type(4))) float float4v;

union u8pack { short8v v; unsigned short u[8]; };

static __device__ __forceinline__ float bf2f(unsigned short u) {
  return __uint_as_float(((unsigned int)u) << 16);
}
static __device__ __forceinline__ unsigned short f2bf(float f) {
  unsigned int u = __float_as_uint(f);
  u = (u + 0x7FFFu + ((u >> 16) & 1u)) >> 16;
  return (unsigned short)u;
}

// ---------------- init: zero cnt+stats, pack w fp32 [240][480] -> bf16 frag order ----------
// wfrag ushort idx: kc*7680 + m*512 + lane*8 + j  holds w[m*16+ln][kc*32+q*8+j], lane=q*16+ln
__global__ void k_init(int* __restrict__ cnt, float* __restrict__ stats,
                       const float* __restrict__ w, unsigned short* __restrict__ wfrag) {
  int g = blockIdx.x * 256 + threadIdx.x;
  if (g < NB * R3) cnt[g] = 0;
  if (g < 1024) stats[g] = 0.0f;
  if (g < 14400) {
    int kc = g / 960, rem = g % 960;
    int m = rem >> 6, l = rem & 63;
    int ln = l & 15, q = l >> 4;
    const float* src = w + (size_t)(m * 16 + ln) * CH2 + kc * 32 + q * 8;
    u8pack pk;
#pragma unroll
    for (int j = 0; j < 8; j++) pk.u[j] = f2bf(src[j]);
    *(short8v*)&wfrag[(size_t)g * 8] = pk.v;
  }
}

// ---------------- per-batch coord mean + scale ----------------
__global__ void k_coord_stats(const float* __restrict__ coords, float* __restrict__ ms) {
  __shared__ float red[256];
  __shared__ float mean[3];
  int b = blockIdx.x, t = threadIdx.x;
  const float* cb = coords + (size_t)b * 3 * NPT;
  float s0 = 0.f, s1 = 0.f, s2 = 0.f;
  for (int i = t; i < NPT; i += 256) {
    s0 += cb[i]; s1 += cb[NPT + i]; s2 += cb[2 * NPT + i];
  }
  float sv[3] = {s0, s1, s2};
  for (int d = 0; d < 3; d++) {
    red[t] = sv[d]; __syncthreads();
    for (int k = 128; k > 0; k >>= 1) { if (t < k) red[t] += red[t + k]; __syncthreads(); }
    if (t == 0) mean[d] = red[0] * (1.0f / NPT);
    __syncthreads();
  }
  float m0 = mean[0], m1 = mean[1], m2 = mean[2];
  float mx = 0.f;
  for (int i = t; i < NPT; i += 256) {
    float dx = cb[i] - m0, dy = cb[NPT + i] - m1, dz = cb[2 * NPT + i] - m2;
    float nsq = dx * dx + dy * dy + dz * dz;
    mx = fmaxf(mx, nsq);
  }
  red[t] = mx; __syncthreads();
  for (int k = 128; k > 0; k >>= 1) { if (t < k) red[t] = fmaxf(red[t], red[t + k]); __syncthreads(); }
  if (t == 0) {
    ms[b * 4 + 0] = m0; ms[b * 4 + 1] = m1; ms[b * 4 + 2] = m2;
    ms[b * 4 + 3] = sqrtf(red[0]) * 2.0f;  // EPS_NORM = 0
  }
}

// ---------------- nc output + voxel id + histogram ----------------
__global__ void k_pos_nc(const float* __restrict__ coords, const float* __restrict__ ms,
                         float* __restrict__ ncout, int* __restrict__ pos, int* __restrict__ cnt) {
  int g = blockIdx.x * 256 + threadIdx.x;  // 0 .. NB*NPT-1
  int b = g >> 15, i = g & (NPT - 1);
  const float* cb = coords + (size_t)b * 3 * NPT;
  float scale = ms[b * 4 + 3];
  int vox[3];
#pragma unroll
  for (int d = 0; d < 3; d++) {
    float v = (cb[(size_t)d * NPT + i] - ms[b * 4 + d]) / scale + 0.5f;
    v = fminf(fmaxf(v * (float)RR, 0.0f), (float)(RR - 1));
    ncout[((size_t)(b * 3 + d)) * NPT + i] = v;
    vox[d] = (int)rintf(v);  // round-half-even, matches jnp.round
  }
  int p = (b << 15) | (vox[0] + (vox[1] << 5) + (vox[2] << 10));
  pos[g] = p;
  atomicAdd(&cnt[p], 1);
}

// ---------------- exclusive scan per batch (32768 entries) ----------------
__global__ void k_scan(const int* __restrict__ cnt, int* __restrict__ offs) {
  __shared__ int part[1024];
  int b = blockIdx.x, t = threadIdx.x;
  const int base = b * R3;
  int local[32];
  int s = 0;
#pragma unroll
  for (int j = 0; j < 32; j++) { local[j] = cnt[base + t * 32 + j]; s += local[j]; }
  part[t] = s; __syncthreads();
  for (int d = 1; d < 1024; d <<= 1) {
    int v = (t >= d) ? part[t - d] : 0;
    __syncthreads();
    part[t] += v;
    __syncthreads();
  }
  int run = (t == 0) ? 0 : part[t - 1];
#pragma unroll
  for (int j = 0; j < 32; j++) { offs[base + t * 32 + j] = run; run += local[j]; }
}

// ---------------- scatter global point ids into voxel-sorted order ----------------
__global__ void k_scatter(const int* __restrict__ pos, int* __restrict__ offs,
                          int* __restrict__ sorted) {
  int g = blockIdx.x * 256 + threadIdx.x;
  int p = pos[g];
  int slot = atomicAdd(&offs[p], 1);  // offs becomes "end" after this kernel
  sorted[((g >> 15) << 15) + slot] = g;  // g = global row id into ft
}

// ---------------- transpose features [B,C,N] fp32 -> ft[point][240] bf16, coalesced -----
__global__ void k_transpose3(const float* __restrict__ f, unsigned short* __restrict__ ft) {
  __shared__ float tile[CH * 65];  // 62,400 B, pad 65 -> conflict-free both phases
  int p0 = blockIdx.x * 64, b = blockIdx.y;
  int t = threadIdx.x;
  {
    int pp = t & 63, cq = t >> 6;  // cq 0..3
    const float* src = f + ((size_t)b * CH) * NPT + p0 + pp;
#pragma unroll 4
    for (int j = 0; j < 60; ++j) {
      int c = j * 4 + cq;
      tile[c * 65 + pp] = src[(size_t)c * NPT];
    }
  }
  __syncthreads();
  int ch8 = t & 7;
#pragma unroll
  for (int pass = 0; pass < 2; ++pass) {
    int p = pass * 32 + (t >> 3);
    unsigned short* dst = ft + ((size_t)(b * NPT + p0 + p)) * CH;
#pragma unroll
    for (int i = 0; i < 4; ++i) {
      int ch = ch8 + 8 * i;          // 16-byte chunk id, 0..29 valid
      if (ch < 30) {
        u8pack pk;
#pragma unroll
        for (int jj = 0; jj < 8; ++jj) pk.u[jj] = f2bf(tile[(ch * 8 + jj) * 65 + p]);
        *(short8v*)&dst[ch * 8] = pk.v;
      }
    }
  }
}

// ---------------- per-voxel max/min gather -> feaf in B-fragment order ----------------
// feaf layout ushort idx: ((b*2048+cg)*15 + kc)*512 + (q*16+ln)*8 + j
//   holds fea[b][col=cg*16+ln][k=kc*32+q*8+j];  k<240: max ch k; k>=240: min ch k-240
__global__ void k_voxel3(const int* __restrict__ cnt, const int* __restrict__ offs,
                         const int* __restrict__ sorted, const unsigned short* __restrict__ ft,
                         unsigned short* __restrict__ feaf) {
  int wave = threadIdx.x >> 6, lane = threadIdx.x & 63;
  int sub = lane >> 5, l = lane & 31;
  if (l >= 30) return;
  int v = blockIdx.x * 8 + wave * 2 + sub;   // global voxel id
  int b = v >> 15, lv = v & 32767;
  int cg = lv >> 4, ln = lv & 15;
  unsigned short* base = feaf + ((size_t)(b * 2048 + cg) * 15) * 512;
  int t0 = l, t1 = 30 + l;
  size_t off0 = (size_t)(t0 >> 2) * 512 + (size_t)(((t0 & 3) * 16 + ln)) * 8;
  size_t off1 = (size_t)(t1 >> 2) * 512 + (size_t)(((t1 & 3) * 16 + ln)) * 8;
  int n = cnt[v];
  if (n == 0) {
    u8pack z;
#pragma unroll
    for (int j = 0; j < 8; j++) z.u[j] = 0;
    *(short8v*)(base + off0) = z.v;
    *(short8v*)(base + off1) = z.v;
    return;
  }
  int start = offs[v] - n;
  const int* sp = sorted + (b << 15) + start;
  float mx[8], mn[8];
#pragma unroll
  for (int j = 0; j < 8; j++) { mx[j] = -__builtin_inff(); mn[j] = __builtin_inff(); }
  int j = 0;
  for (; j + 2 <= n; j += 2) {
    int r0 = sp[j], r1 = sp[j + 1];
    u8pack u0, u1;
    u0.v = *(const short8v*)(ft + (size_t)r0 * CH + l * 8);
    u1.v = *(const short8v*)(ft + (size_t)r1 * CH + l * 8);
#pragma unroll
    for (int k = 0; k < 8; k++) {
      float a = bf2f(u0.u[k]), c = bf2f(u1.u[k]);
      mx[k] = fmaxf(mx[k], fmaxf(a, c));
      mn[k] = fminf(mn[k], fminf(a, c));
    }
  }
  if (j < n) {
    int r0 = sp[j];
    u8pack u0;
    u0.v = *(const short8v*)(ft + (size_t)r0 * CH + l * 8);
#pragma unroll
    for (int k = 0; k < 8; k++) {
      float a = bf2f(u0.u[k]);
      mx[k] = fmaxf(mx[k], a);
      mn[k] = fminf(mn[k], a);
    }
  }
  u8pack omx, omn;
#pragma unroll
  for (int k = 0; k < 8; k++) { omx.u[k] = f2bf(mx[k]); omn.u[k] = f2bf(mn[k]); }
  *(short8v*)(base + off0) = omx.v;
  *(short8v*)(base + off1) = omn.v;
}

// ---------------- GEMM: LDS-staged w frags (4 K-phases), contiguous b-loads, fused stats ----
__global__ __launch_bounds__(512, 2) void k_gemm3(const unsigned short* __restrict__ wfrag,
                                                  const unsigned short* __restrict__ feaf,
                                                  const float* __restrict__ bias,
                                                  float* __restrict__ out,
                                                  float* __restrict__ gstats) {
  __shared__ unsigned short wl[4 * 7680];   // 61,440 B: up to 4 kc-chunks of w frags
  __shared__ float bstats[2 * CH];
  for (int i = threadIdx.x; i < 2 * CH; i += 512) bstats[i] = 0.0f;

  int bz = blockIdx.z;
  int wave = threadIdx.x >> 6, lane = threadIdx.x & 63;
  int ln = lane & 15, q = lane >> 4;
  int v0 = blockIdx.x * 256 + wave * 32;
  int cg0 = v0 >> 4;

  float4v acc[15][2];
#pragma unroll
  for (int m = 0; m < 15; m++) {
    acc[m][0] = (float4v){0.f, 0.f, 0.f, 0.f};
    acc[m][1] = (float4v){0.f, 0.f, 0.f, 0.f};
  }

  // b0: cols v0+ln (cg0), b1: cols v0+16+ln (cg0+1); contiguous 1KB per wave-load
  const unsigned short* fb = feaf + ((size_t)(bz * 2048 + cg0) * 15) * 512 + lane * 8;

  for (int ph = 0; ph < 4; ++ph) {
    int kc0 = ph * 4;
    int nkc = (ph == 3) ? 3 : 4;
    const unsigned short* wsrc = wfrag + (size_t)kc0 * 7680;
    for (int i = threadIdx.x; i < nkc * 960; i += 512)
      *(int4*)&wl[i * 8] = *(const int4*)&wsrc[(size_t)i * 8];
    // prefetch all b-frags of this phase while LDS fill is in flight
    short8v bb0[4], bb1[4];
    for (int kcL = 0; kcL < nkc; ++kcL) {
      int kc = kc0 + kcL;
      bb0[kcL] = *(const short8v*)(fb + (size_t)kc * 512);
      bb1[kcL] = *(const short8v*)(fb + (size_t)(15 + kc) * 512);
    }
    __syncthreads();
    for (int kcL = 0; kcL < nkc; ++kcL) {
      const unsigned short* wp = wl + kcL * 7680 + lane * 8;
      short8v b0 = bb0[kcL], b1 = bb1[kcL];
#pragma unroll
      for (int m = 0; m < 15; ++m) {
        short8v a = *(const short8v*)(wp + m * 512);
        acc[m][0] = __builtin_amdgcn_mfma_f32_16x16x32_bf16(a, b0, acc[m][0], 0, 0, 0);
        acc[m][1] = __builtin_amdgcn_mfma_f32_16x16x32_bf16(a, b1, acc[m][1], 0, 0, 0);
      }
    }
    __syncthreads();
  }

  // epilogue: y = acc + bias; store; per-channel sum/sumsq reduction
  float* o0 = out + (size_t)bz * CH * R3 + v0 + ln;
  float* o1 = o0 + 16;
#pragma unroll
  for (int m = 0; m < 15; ++m) {
    int cbase = m * 16 + q * 4;
    float s[4], sq[4];
#pragma unroll
    for (int r = 0; r < 4; ++r) {
      float bb = bias[cbase + r];
      float y0 = acc[m][0][r] + bb;
      float y1 = acc[m][1][r] + bb;
      o0[(size_t)(cbase + r) * R3] = y0;
      o1[(size_t)(cbase + r) * R3] = y1;
      s[r] = y0 + y1;
      sq[r] = y0 * y0 + y1 * y1;
    }
#pragma unroll
    for (int off = 1; off < 16; off <<= 1) {
#pragma unroll
      for (int r = 0; r < 4; ++r) {
        s[r] += __shfl_xor(s[r], off);
        sq[r] += __shfl_xor(sq[r], off);
      }
    }
    if (ln == 0) {
#pragma unroll
      for (int r = 0; r < 4; ++r) {
        atomicAdd(&bstats[cbase + r], s[r]);
        atomicAdd(&bstats[CH + cbase + r], sq[r]);
      }
    }
  }
  __syncthreads();
  for (int i = threadIdx.x; i < 2 * CH; i += 512) atomicAdd(&gstats[i], bstats[i]);
}

// ---------------- apply BN (stats->scale inline) + swish in place ----------------
__global__ void k_apply(float* __restrict__ y, const float* __restrict__ stats,
                        const float* __restrict__ gamma, const float* __restrict__ beta) {
  int g = blockIdx.x * 256 + threadIdx.x;  // float4 chunk id
  int c = (g >> 13) % CH;                  // 8192 chunks per (b,c) row
  const float ninv = 1.0f / (float)(NB * R3);
  float mean = stats[c] * ninv;
  float var = stats[CH + c] * ninv - mean * mean;
  float s = gamma[c] * rsqrtf(var + 1e-5f);
  float h = beta[c] - mean * s;
  float4 v = ((const float4*)y)[g];
  float t0 = v.x * s + h; v.x = t0 / (1.0f + __expf(-t0));
  float t1 = v.y * s + h; v.y = t1 / (1.0f + __expf(-t1));
  float t2 = v.z * s + h; v.z = t2 / (1.0f + __expf(-t2));
  float t3 = v.w * s + h; v.w = t3 / (1.0f + __expf(-t3));
  ((float4*)y)[g] = v;
}

extern "C" void kernel_launch(void* const* d_in, const int* in_sizes, int n_in,
                              void* d_out, int out_size, void* d_ws, size_t ws_size,
                              hipStream_t stream) {
  const float* features = (const float*)d_in[0];
  const float* coords   = (const float*)d_in[1];
  const float* w        = (const float*)d_in[2];
  const float* bias     = (const float*)d_in[3];
  const float* gamma    = (const float*)d_in[4];
  const float* beta     = (const float*)d_in[5];
  float* out = (float*)d_out;

  char* ws = (char*)d_ws;
  size_t off = 0;
  float* ms    = (float*)(ws + off); off += 256;
  float* stats = (float*)(ws + off); off += 4096;
  int* pos     = (int*)(ws + off);   off += (size_t)NB * NPT * 4;
  int* cnt     = (int*)(ws + off);   off += (size_t)NB * R3 * 4;
  int* offs    = (int*)(ws + off);   off += (size_t)NB * R3 * 4;
  int* sorted  = (int*)(ws + off);   off += (size_t)NB * NPT * 4;
  unsigned short* wfrag = (unsigned short*)(ws + off); off += (size_t)CH * CH2 * 2;
  unsigned short* ft    = (unsigned short*)(ws + off); off += (size_t)NB * NPT * CH * 2;
  unsigned short* feaf  = (unsigned short*)(ws + off); off += (size_t)NB * R3 * CH2 * 2;

  float* ncout = out + Y_ELEMS;

  k_init<<<516, 256, 0, stream>>>(cnt, stats, w, wfrag);
  k_coord_stats<<<4, 256, 0, stream>>>(coords, ms);
  k_pos_nc<<<512, 256, 0, stream>>>(coords, ms, ncout, pos, cnt);
  k_scan<<<4, 1024, 0, stream>>>(cnt, offs);
  k_scatter<<<512, 256, 0, stream>>>(pos, offs, sorted);
  k_transpose3<<<dim3(512, 4), 256, 0, stream>>>(features, ft);
  k_voxel3<<<NB * R3 / 8, 256, 0, stream>>>(cnt, offs, sorted, ft, feaf);
  k_gemm3<<<dim3(128, 1, NB), 512, 0, stream>>>(wfrag, feaf, bias, out, stats);
  k_apply<<<Y_ELEMS / 1024, 256, 0, stream>>>(out, stats, gamma, beta);
}

// Round 4
// 558.877 us; speedup vs baseline: 1.1760x; 1.1760x over previous
//
#include <hip/hip_runtime.h>
#include <cstdint>
#include <cstddef>

#define RR 32
#define R3 32768
#define NPT 32768
#define CH 240
#define CH2 480
#define NB 4
#define Y_ELEMS 31457280   // 4*240*32768

typedef __attribute__((ext_vector_type(8))) short short8v;
typedef __attribute__((ext_vector_type(4))) float float4v;

union u8pack { short8v v; unsigned short u[8]; };

static __device__ __forceinline__ float bf2f(unsigned short u) {
  return __uint_as_float(((unsigned int)u) << 16);
}
static __device__ __forceinline__ unsigned short f2bf(float f) {
  unsigned int u = __float_as_uint(f);
  u = (u + 0x7FFFu + ((u >> 16) & 1u)) >> 16;
  return (unsigned short)u;
}

// ---------------- init: zero cnt+stats, pack w fp32 [240][480] -> bf16 frag order ----------
// wfrag ushort idx: kc*7680 + m*512 + lane*8 + j  holds w[m*16+ln][kc*32+q*8+j], lane=q*16+ln
__global__ void k_init(int* __restrict__ cnt, float* __restrict__ stats,
                       const float* __restrict__ w, unsigned short* __restrict__ wfrag) {
  int g = blockIdx.x * 256 + threadIdx.x;
  if (g < NB * R3) cnt[g] = 0;
  if (g < 1024) stats[g] = 0.0f;
  if (g < 14400) {
    int kc = g / 960, rem = g % 960;
    int m = rem >> 6, l = rem & 63;
    int ln = l & 15, q = l >> 4;
    const float* src = w + (size_t)(m * 16 + ln) * CH2 + kc * 32 + q * 8;
    u8pack pk;
#pragma unroll
    for (int j = 0; j < 8; j++) pk.u[j] = f2bf(src[j]);
    *(short8v*)&wfrag[(size_t)g * 8] = pk.v;
  }
}

// ---------------- per-batch coord mean + scale (1024 thr, float4) ----------------
__global__ __launch_bounds__(1024) void k_coord_stats(const float* __restrict__ coords,
                                                      float* __restrict__ ms) {
  __shared__ float red[1024];
  __shared__ float mean[3];
  int b = blockIdx.x, t = threadIdx.x;
  const float4* cb4 = (const float4*)(coords + (size_t)b * 3 * NPT);
  float s[3] = {0.f, 0.f, 0.f};
  for (int i = t; i < NPT / 4; i += 1024) {
#pragma unroll
    for (int d = 0; d < 3; d++) {
      float4 v = cb4[d * (NPT / 4) + i];
      s[d] += (v.x + v.y) + (v.z + v.w);
    }
  }
  for (int d = 0; d < 3; d++) {
    red[t] = s[d]; __syncthreads();
    for (int k = 512; k > 0; k >>= 1) { if (t < k) red[t] += red[t + k]; __syncthreads(); }
    if (t == 0) mean[d] = red[0] * (1.0f / NPT);
    __syncthreads();
  }
  float m0 = mean[0], m1 = mean[1], m2 = mean[2];
  float mx = 0.f;
  for (int i = t; i < NPT / 4; i += 1024) {
    float4 x = cb4[i], y = cb4[NPT / 4 + i], z = cb4[2 * (NPT / 4) + i];
    float dx, dy, dz, n;
    dx = x.x - m0; dy = y.x - m1; dz = z.x - m2; n = dx * dx + dy * dy + dz * dz; mx = fmaxf(mx, n);
    dx = x.y - m0; dy = y.y - m1; dz = z.y - m2; n = dx * dx + dy * dy + dz * dz; mx = fmaxf(mx, n);
    dx = x.z - m0; dy = y.z - m1; dz = z.z - m2; n = dx * dx + dy * dy + dz * dz; mx = fmaxf(mx, n);
    dx = x.w - m0; dy = y.w - m1; dz = z.w - m2; n = dx * dx + dy * dy + dz * dz; mx = fmaxf(mx, n);
  }
  red[t] = mx; __syncthreads();
  for (int k = 512; k > 0; k >>= 1) { if (t < k) red[t] = fmaxf(red[t], red[t + k]); __syncthreads(); }
  if (t == 0) {
    ms[b * 4 + 0] = m0; ms[b * 4 + 1] = m1; ms[b * 4 + 2] = m2;
    ms[b * 4 + 3] = sqrtf(red[0]) * 2.0f;  // EPS_NORM = 0
  }
}

// ---------------- nc output + voxel id + histogram ----------------
__global__ void k_pos_nc(const float* __restrict__ coords, const float* __restrict__ ms,
                         float* __restrict__ ncout, int* __restrict__ pos, int* __restrict__ cnt) {
  int g = blockIdx.x * 256 + threadIdx.x;  // 0 .. NB*NPT-1
  int b = g >> 15, i = g & (NPT - 1);
  const float* cb = coords + (size_t)b * 3 * NPT;
  float scale = ms[b * 4 + 3];
  int vox[3];
#pragma unroll
  for (int d = 0; d < 3; d++) {
    float v = (cb[(size_t)d * NPT + i] - ms[b * 4 + d]) / scale + 0.5f;
    v = fminf(fmaxf(v * (float)RR, 0.0f), (float)(RR - 1));
    ncout[((size_t)(b * 3 + d)) * NPT + i] = v;
    vox[d] = (int)rintf(v);  // round-half-even, matches jnp.round
  }
  int p = (b << 15) | (vox[0] + (vox[1] << 5) + (vox[2] << 10));
  pos[g] = p;
  atomicAdd(&cnt[p], 1);
}

// ---------------- exclusive scan per batch (32768 entries) ----------------
__global__ void k_scan(const int* __restrict__ cnt, int* __restrict__ offs) {
  __shared__ int part[1024];
  int b = blockIdx.x, t = threadIdx.x;
  const int base = b * R3;
  int local[32];
  int s = 0;
#pragma unroll
  for (int j = 0; j < 32; j++) { local[j] = cnt[base + t * 32 + j]; s += local[j]; }
  part[t] = s; __syncthreads();
  for (int d = 1; d < 1024; d <<= 1) {
    int v = (t >= d) ? part[t - d] : 0;
    __syncthreads();
    part[t] += v;
    __syncthreads();
  }
  int run = (t == 0) ? 0 : part[t - 1];
#pragma unroll
  for (int j = 0; j < 32; j++) { offs[base + t * 32 + j] = run; run += local[j]; }
}

// ---------------- scatter global point ids into voxel-sorted order ----------------
__global__ void k_scatter(const int* __restrict__ pos, int* __restrict__ offs,
                          int* __restrict__ sorted) {
  int g = blockIdx.x * 256 + threadIdx.x;
  int p = pos[g];
  int slot = atomicAdd(&offs[p], 1);  // offs becomes "end" after this kernel
  sorted[((g >> 15) << 15) + slot] = g;  // g = global point row id into ft
}

// ---------------- transpose features [B,C,N] fp32 -> ft[point][240] bf16, coalesced -----
__global__ void k_transpose3(const float* __restrict__ f, unsigned short* __restrict__ ft) {
  __shared__ float tile[CH * 65];  // 62,400 B
  int p0 = blockIdx.x * 64, b = blockIdx.y;
  int t = threadIdx.x;
  {
    int pp = t & 63, cq = t >> 6;  // cq 0..3
    const float* src = f + ((size_t)b * CH) * NPT + p0 + pp;
#pragma unroll 4
    for (int j = 0; j < 60; ++j) {
      int c = j * 4 + cq;
      tile[c * 65 + pp] = src[(size_t)c * NPT];
    }
  }
  __syncthreads();
  int ch8 = t & 7;
#pragma unroll
  for (int pass = 0; pass < 2; ++pass) {
    int p = pass * 32 + (t >> 3);
    unsigned short* dst = ft + ((size_t)(b * NPT + p0 + p)) * CH;
#pragma unroll
    for (int i = 0; i < 4; ++i) {
      int ch = ch8 + 8 * i;          // 16-byte chunk id, 0..29 valid
      if (ch < 30) {
        u8pack pk;
#pragma unroll
        for (int jj = 0; jj < 8; ++jj) pk.u[jj] = f2bf(tile[(ch * 8 + jj) * 65 + p]);
        *(short8v*)&dst[ch * 8] = pk.v;
      }
    }
  }
}

// ---------------- per-voxel max/min gather -> LDS cg-image -> coalesced feaf ----------------
// feaf layout ushort idx: ((b*2048+cg)*15 + kc)*512 + (q*16+ln)*8 + j
//   holds fea[b][col=cg*16+ln][k=kc*32+q*8+j];  k<240: max ch k; k>=240: min ch k-240
__global__ __launch_bounds__(256) void k_voxel4(const int* __restrict__ cnt,
                                                const int* __restrict__ offs,
                                                const int* __restrict__ sorted,
                                                const unsigned short* __restrict__ ft,
                                                unsigned short* __restrict__ feaf) {
  __shared__ unsigned short sh[7680];   // 15,360 B: exact feaf image of this cg
  int bcg = blockIdx.x;                 // b*2048 + cg
  int b = bcg >> 11;
  int wave = threadIdx.x >> 6, lane = threadIdx.x & 63;
  int sub = lane >> 5, l = lane & 31;
  int vbase = bcg << 4;                 // global voxel id base (= (b<<15) + cg*16)
#pragma unroll
  for (int it = 0; it < 2; ++it) {
    int ln = wave + 8 * it + 4 * sub;   // 0..15, bijective
    if (l < 30) {
      int v = vbase + ln;
      int t0 = l, t1 = 30 + l;
      int idx0 = (t0 >> 2) * 512 + ((t0 & 3) * 16 + ln) * 8;
      int idx1 = (t1 >> 2) * 512 + ((t1 & 3) * 16 + ln) * 8;
      int n = cnt[v];
      if (n == 0) {
        u8pack z;
#pragma unroll
        for (int j = 0; j < 8; j++) z.u[j] = 0;
        *(short8v*)&sh[idx0] = z.v;
        *(short8v*)&sh[idx1] = z.v;
      } else {
        int start = offs[v] - n;
        const int* sp = sorted + (b << 15) + start;
        float mx[8], mn[8];
#pragma unroll
        for (int j = 0; j < 8; j++) { mx[j] = -__builtin_inff(); mn[j] = __builtin_inff(); }
        int j = 0;
        for (; j + 2 <= n; j += 2) {
          int r0 = sp[j], r1 = sp[j + 1];
          u8pack u0, u1;
          u0.v = *(const short8v*)(ft + (size_t)r0 * CH + l * 8);
          u1.v = *(const short8v*)(ft + (size_t)r1 * CH + l * 8);
#pragma unroll
          for (int k = 0; k < 8; k++) {
            float a = bf2f(u0.u[k]), c = bf2f(u1.u[k]);
            mx[k] = fmaxf(mx[k], fmaxf(a, c));
            mn[k] = fminf(mn[k], fminf(a, c));
          }
        }
        if (j < n) {
          int r0 = sp[j];
          u8pack u0;
          u0.v = *(const short8v*)(ft + (size_t)r0 * CH + l * 8);
#pragma unroll
          for (int k = 0; k < 8; k++) {
            float a = bf2f(u0.u[k]);
            mx[k] = fmaxf(mx[k], a);
            mn[k] = fminf(mn[k], a);
          }
        }
        u8pack omx, omn;
#pragma unroll
        for (int k = 0; k < 8; k++) { omx.u[k] = f2bf(mx[k]); omn.u[k] = f2bf(mn[k]); }
        *(short8v*)&sh[idx0] = omx.v;
        *(short8v*)&sh[idx1] = omn.v;
      }
    }
  }
  __syncthreads();
  unsigned short* dst = feaf + (size_t)bcg * 7680;
  for (int i = threadIdx.x; i < 960; i += 256)
    *(int4*)&dst[i * 8] = *(const int4*)&sh[i * 8];
}

// ---------------- GEMM: LDS-staged w frags (4 K-phases), contiguous b-loads, fused stats ----
// 256 thr / 2 blocks per CU: 2 waves/SIMD -> 256 unified regs/wave (acc=120 AGPR fits).
__global__ __launch_bounds__(256, 2) void k_gemm4(const unsigned short* __restrict__ wfrag,
                                                  const unsigned short* __restrict__ feaf,
                                                  const float* __restrict__ bias,
                                                  float* __restrict__ out,
                                                  float* __restrict__ gstats) {
  __shared__ unsigned short wl[4 * 7680];   // 61,440 B: up to 4 kc-chunks of w frags
  __shared__ float bstats[2 * CH];
  for (int i = threadIdx.x; i < 2 * CH; i += 256) bstats[i] = 0.0f;

  int bz = blockIdx.z;
  int wave = threadIdx.x >> 6, lane = threadIdx.x & 63;
  int ln = lane & 15, q = lane >> 4;
  int v0 = blockIdx.x * 128 + wave * 32;
  int cg0 = v0 >> 4;

  float4v acc[15][2];
#pragma unroll
  for (int m = 0; m < 15; m++) {
    acc[m][0] = (float4v){0.f, 0.f, 0.f, 0.f};
    acc[m][1] = (float4v){0.f, 0.f, 0.f, 0.f};
  }

  // b0: cols v0+ln (cg0), b1: cols v0+16+ln (cg0+1); contiguous 1KB per wave-load
  const unsigned short* fb = feaf + ((size_t)(bz * 2048 + cg0) * 15) * 512 + lane * 8;

  for (int ph = 0; ph < 4; ++ph) {
    int kc0 = ph * 4;
    int nkc = (ph == 3) ? 3 : 4;
    const unsigned short* wsrc = wfrag + (size_t)kc0 * 7680;
    for (int i = threadIdx.x; i < nkc * 960; i += 256)
      *(int4*)&wl[i * 8] = *(const int4*)&wsrc[(size_t)i * 8];
    // prefetch all b-frags of this phase while LDS fill is in flight
    short8v bb0[4], bb1[4];
    for (int kcL = 0; kcL < nkc; ++kcL) {
      int kc = kc0 + kcL;
      bb0[kcL] = *(const short8v*)(fb + (size_t)kc * 512);
      bb1[kcL] = *(const short8v*)(fb + (size_t)(15 + kc) * 512);
    }
    __syncthreads();
    for (int kcL = 0; kcL < nkc; ++kcL) {
      const unsigned short* wp = wl + kcL * 7680 + lane * 8;
      short8v b0 = bb0[kcL], b1 = bb1[kcL];
#pragma unroll
      for (int m = 0; m < 15; ++m) {
        short8v a = *(const short8v*)(wp + m * 512);
        acc[m][0] = __builtin_amdgcn_mfma_f32_16x16x32_bf16(a, b0, acc[m][0], 0, 0, 0);
        acc[m][1] = __builtin_amdgcn_mfma_f32_16x16x32_bf16(a, b1, acc[m][1], 0, 0, 0);
      }
    }
    __syncthreads();
  }

  // epilogue: y = acc + bias; store; per-channel sum/sumsq reduction
  float* o0 = out + (size_t)bz * CH * R3 + v0 + ln;
  float* o1 = o0 + 16;
#pragma unroll
  for (int m = 0; m < 15; ++m) {
    int cbase = m * 16 + q * 4;
    float s[4], sq[4];
#pragma unroll
    for (int r = 0; r < 4; ++r) {
      float bb = bias[cbase + r];
      float y0 = acc[m][0][r] + bb;
      float y1 = acc[m][1][r] + bb;
      o0[(size_t)(cbase + r) * R3] = y0;
      o1[(size_t)(cbase + r) * R3] = y1;
      s[r] = y0 + y1;
      sq[r] = y0 * y0 + y1 * y1;
    }
#pragma unroll
    for (int off = 1; off < 16; off <<= 1) {
#pragma unroll
      for (int r = 0; r < 4; ++r) {
        s[r] += __shfl_xor(s[r], off);
        sq[r] += __shfl_xor(sq[r], off);
      }
    }
    if (ln == 0) {
#pragma unroll
      for (int r = 0; r < 4; ++r) {
        atomicAdd(&bstats[cbase + r], s[r]);
        atomicAdd(&bstats[CH + cbase + r], sq[r]);
      }
    }
  }
  __syncthreads();
  for (int i = threadIdx.x; i < 2 * CH; i += 256) atomicAdd(&gstats[i], bstats[i]);
}

// ---------------- apply BN (stats->scale inline) + swish in place ----------------
__global__ void k_apply(float* __restrict__ y, const float* __restrict__ stats,
                        const float* __restrict__ gamma, const float* __restrict__ beta) {
  int g = blockIdx.x * 256 + threadIdx.x;  // float4 chunk id
  int c = (g >> 13) % CH;                  // 8192 chunks per (b,c) row
  const float ninv = 1.0f / (float)(NB * R3);
  float mean = stats[c] * ninv;
  float var = stats[CH + c] * ninv - mean * mean;
  float s = gamma[c] * rsqrtf(var + 1e-5f);
  float h = beta[c] - mean * s;
  float4 v = ((const float4*)y)[g];
  float t0 = v.x * s + h; v.x = t0 / (1.0f + __expf(-t0));
  float t1 = v.y * s + h; v.y = t1 / (1.0f + __expf(-t1));
  float t2 = v.z * s + h; v.z = t2 / (1.0f + __expf(-t2));
  float t3 = v.w * s + h; v.w = t3 / (1.0f + __expf(-t3));
  ((float4*)y)[g] = v;
}

extern "C" void kernel_launch(void* const* d_in, const int* in_sizes, int n_in,
                              void* d_out, int out_size, void* d_ws, size_t ws_size,
                              hipStream_t stream) {
  const float* features = (const float*)d_in[0];
  const float* coords   = (const float*)d_in[1];
  const float* w        = (const float*)d_in[2];
  const float* bias     = (const float*)d_in[3];
  const float* gamma    = (const float*)d_in[4];
  const float* beta     = (const float*)d_in[5];
  float* out = (float*)d_out;

  char* ws = (char*)d_ws;
  size_t off = 0;
  float* ms    = (float*)(ws + off); off += 256;
  float* stats = (float*)(ws + off); off += 4096;
  int* pos     = (int*)(ws + off);   off += (size_t)NB * NPT * 4;
  int* cnt     = (int*)(ws + off);   off += (size_t)NB * R3 * 4;
  int* offs    = (int*)(ws + off);   off += (size_t)NB * R3 * 4;
  int* sorted  = (int*)(ws + off);   off += (size_t)NB * NPT * 4;
  unsigned short* wfrag = (unsigned short*)(ws + off); off += (size_t)CH * CH2 * 2;
  unsigned short* ft    = (unsigned short*)(ws + off); off += (size_t)NB * NPT * CH * 2;
  unsigned short* feaf  = (unsigned short*)(ws + off); off += (size_t)NB * R3 * CH2 * 2;

  float* ncout = out + Y_ELEMS;

  k_init<<<516, 256, 0, stream>>>(cnt, stats, w, wfrag);
  k_coord_stats<<<4, 1024, 0, stream>>>(coords, ms);
  k_pos_nc<<<512, 256, 0, stream>>>(coords, ms, ncout, pos, cnt);
  k_scan<<<4, 1024, 0, stream>>>(cnt, offs);
  k_scatter<<<512, 256, 0, stream>>>(pos, offs, sorted);
  k_transpose3<<<dim3(512, 4), 256, 0, stream>>>(features, ft);
  k_voxel4<<<NB * 2048, 256, 0, stream>>>(cnt, offs, sorted, ft, feaf);
  k_gemm4<<<dim3(256, 1, NB), 256, 0, stream>>>(wfrag, feaf, bias, out, stats);
  k_apply<<<Y_ELEMS / 1024, 256, 0, stream>>>(out, stats, gamma, beta);
}

// Round 5
// 421.678 us; speedup vs baseline: 1.5586x; 1.3254x over previous
//
#include <hip/hip_runtime.h>
#include <cstdint>
#include <cstddef>

#define RR 32
#define R3 32768
#define NPT 32768
#define CH 240
#define CH2 480
#define NB 4
#define Y_ELEMS 31457280   // 4*240*32768

typedef __attribute__((ext_vector_type(8))) short short8v;
typedef __attribute__((ext_vector_type(4))) float float4v;

union u8pack { short8v v; unsigned short u[8]; };

static __device__ __forceinline__ float bf2f(unsigned short u) {
  return __uint_as_float(((unsigned int)u) << 16);
}
static __device__ __forceinline__ unsigned short f2bf(float f) {
  unsigned int u = __float_as_uint(f);
  u = (u + 0x7FFFu + ((u >> 16) & 1u)) >> 16;
  return (unsigned short)u;
}

// async global->LDS, 16B per lane; l must be wave-uniform, g is per-lane (base + lane*16)
static __device__ __forceinline__ void gl_lds16(const void* g, void* l) {
  __builtin_amdgcn_global_load_lds((const __attribute__((address_space(1))) unsigned int*)g,
                                   (__attribute__((address_space(3))) unsigned int*)l, 16, 0, 0);
}

// ---------------- init: zero cnt+stats, pack w fp32 [240][480] -> bf16 frag order ----------
// wfrag ushort idx: kc*7680 + m*512 + lane*8 + j  holds w[m*16+ln][kc*32+q*8+j], lane=q*16+ln
__global__ void k_init(int* __restrict__ cnt, float* __restrict__ stats,
                       const float* __restrict__ w, unsigned short* __restrict__ wfrag) {
  int g = blockIdx.x * 256 + threadIdx.x;
  if (g < NB * R3) cnt[g] = 0;
  if (g < 1024) stats[g] = 0.0f;
  if (g < 14400) {
    int kc = g / 960, rem = g % 960;
    int m = rem >> 6, l = rem & 63;
    int ln = l & 15, q = l >> 4;
    const float* src = w + (size_t)(m * 16 + ln) * CH2 + kc * 32 + q * 8;
    u8pack pk;
#pragma unroll
    for (int j = 0; j < 8; j++) pk.u[j] = f2bf(src[j]);
    *(short8v*)&wfrag[(size_t)g * 8] = pk.v;
  }
}

// ---------------- per-batch coord mean + scale (1024 thr, float4) ----------------
__global__ __launch_bounds__(1024) void k_coord_stats(const float* __restrict__ coords,
                                                      float* __restrict__ ms) {
  __shared__ float red[1024];
  __shared__ float mean[3];
  int b = blockIdx.x, t = threadIdx.x;
  const float4* cb4 = (const float4*)(coords + (size_t)b * 3 * NPT);
  float s[3] = {0.f, 0.f, 0.f};
  for (int i = t; i < NPT / 4; i += 1024) {
#pragma unroll
    for (int d = 0; d < 3; d++) {
      float4 v = cb4[d * (NPT / 4) + i];
      s[d] += (v.x + v.y) + (v.z + v.w);
    }
  }
  for (int d = 0; d < 3; d++) {
    red[t] = s[d]; __syncthreads();
    for (int k = 512; k > 0; k >>= 1) { if (t < k) red[t] += red[t + k]; __syncthreads(); }
    if (t == 0) mean[d] = red[0] * (1.0f / NPT);
    __syncthreads();
  }
  float m0 = mean[0], m1 = mean[1], m2 = mean[2];
  float mx = 0.f;
  for (int i = t; i < NPT / 4; i += 1024) {
    float4 x = cb4[i], y = cb4[NPT / 4 + i], z = cb4[2 * (NPT / 4) + i];
    float dx, dy, dz, n;
    dx = x.x - m0; dy = y.x - m1; dz = z.x - m2; n = dx * dx + dy * dy + dz * dz; mx = fmaxf(mx, n);
    dx = x.y - m0; dy = y.y - m1; dz = z.y - m2; n = dx * dx + dy * dy + dz * dz; mx = fmaxf(mx, n);
    dx = x.z - m0; dy = y.z - m1; dz = z.z - m2; n = dx * dx + dy * dy + dz * dz; mx = fmaxf(mx, n);
    dx = x.w - m0; dy = y.w - m1; dz = z.w - m2; n = dx * dx + dy * dy + dz * dz; mx = fmaxf(mx, n);
  }
  red[t] = mx; __syncthreads();
  for (int k = 512; k > 0; k >>= 1) { if (t < k) red[t] = fmaxf(red[t], red[t + k]); __syncthreads(); }
  if (t == 0) {
    ms[b * 4 + 0] = m0; ms[b * 4 + 1] = m1; ms[b * 4 + 2] = m2;
    ms[b * 4 + 3] = sqrtf(red[0]) * 2.0f;  // EPS_NORM = 0
  }
}

// ---------------- nc output + voxel id + histogram ----------------
__global__ void k_pos_nc(const float* __restrict__ coords, const float* __restrict__ ms,
                         float* __restrict__ ncout, int* __restrict__ pos, int* __restrict__ cnt) {
  int g = blockIdx.x * 256 + threadIdx.x;  // 0 .. NB*NPT-1
  int b = g >> 15, i = g & (NPT - 1);
  const float* cb = coords + (size_t)b * 3 * NPT;
  float scale = ms[b * 4 + 3];
  int vox[3];
#pragma unroll
  for (int d = 0; d < 3; d++) {
    float v = (cb[(size_t)d * NPT + i] - ms[b * 4 + d]) / scale + 0.5f;
    v = fminf(fmaxf(v * (float)RR, 0.0f), (float)(RR - 1));
    ncout[((size_t)(b * 3 + d)) * NPT + i] = v;
    vox[d] = (int)rintf(v);  // round-half-even, matches jnp.round
  }
  int p = (b << 15) | (vox[0] + (vox[1] << 5) + (vox[2] << 10));
  pos[g] = p;
  atomicAdd(&cnt[p], 1);
}

// ---------------- exclusive scan per batch (32768 entries) ----------------
__global__ void k_scan(const int* __restrict__ cnt, int* __restrict__ offs) {
  __shared__ int part[1024];
  int b = blockIdx.x, t = threadIdx.x;
  const int base = b * R3;
  int local[32];
  int s = 0;
#pragma unroll
  for (int j = 0; j < 32; j++) { local[j] = cnt[base + t * 32 + j]; s += local[j]; }
  part[t] = s; __syncthreads();
  for (int d = 1; d < 1024; d <<= 1) {
    int v = (t >= d) ? part[t - d] : 0;
    __syncthreads();
    part[t] += v;
    __syncthreads();
  }
  int run = (t == 0) ? 0 : part[t - 1];
#pragma unroll
  for (int j = 0; j < 32; j++) { offs[base + t * 32 + j] = run; run += local[j]; }
}

// ---------------- scatter global point ids into voxel-sorted order ----------------
__global__ void k_scatter(const int* __restrict__ pos, int* __restrict__ offs,
                          int* __restrict__ sorted) {
  int g = blockIdx.x * 256 + threadIdx.x;
  int p = pos[g];
  int slot = atomicAdd(&offs[p], 1);  // offs becomes "end" after this kernel
  sorted[((g >> 15) << 15) + slot] = g;  // g = global point row id into ft
}

// ---------------- transpose features [B,C,N] fp32 -> ft[point][240] bf16, coalesced -----
__global__ void k_transpose3(const float* __restrict__ f, unsigned short* __restrict__ ft) {
  __shared__ float tile[CH * 65];  // 62,400 B
  int p0 = blockIdx.x * 64, b = blockIdx.y;
  int t = threadIdx.x;
  {
    int pp = t & 63, cq = t >> 6;  // cq 0..3
    const float* src = f + ((size_t)b * CH) * NPT + p0 + pp;
#pragma unroll 4
    for (int j = 0; j < 60; ++j) {
      int c = j * 4 + cq;
      tile[c * 65 + pp] = src[(size_t)c * NPT];
    }
  }
  __syncthreads();
  int ch8 = t & 7;
#pragma unroll
  for (int pass = 0; pass < 2; ++pass) {
    int p = pass * 32 + (t >> 3);
    unsigned short* dst = ft + ((size_t)(b * NPT + p0 + p)) * CH;
#pragma unroll
    for (int i = 0; i < 4; ++i) {
      int ch = ch8 + 8 * i;          // 16-byte chunk id, 0..29 valid
      if (ch < 30) {
        u8pack pk;
#pragma unroll
        for (int jj = 0; jj < 8; ++jj) pk.u[jj] = f2bf(tile[(ch * 8 + jj) * 65 + p]);
        *(short8v*)&dst[ch * 8] = pk.v;
      }
    }
  }
}

// ---------------- per-voxel max/min gather -> LDS cg-image -> coalesced feaf ----------------
// feaf layout ushort idx: ((b*2048+cg)*15 + kc)*512 + (q*16+ln)*8 + j
//   holds fea[b][col=cg*16+ln][k=kc*32+q*8+j];  k<240: max ch k; k>=240: min ch k-240
__global__ __launch_bounds__(256) void k_voxel4(const int* __restrict__ cnt,
                                                const int* __restrict__ offs,
                                                const int* __restrict__ sorted,
                                                const unsigned short* __restrict__ ft,
                                                unsigned short* __restrict__ feaf) {
  __shared__ unsigned short sh[7680];   // 15,360 B: exact feaf image of this cg
  int bcg = blockIdx.x;                 // b*2048 + cg
  int b = bcg >> 11;
  int wave = threadIdx.x >> 6, lane = threadIdx.x & 63;
  int sub = lane >> 5, l = lane & 31;
  int vbase = bcg << 4;                 // global voxel id base (= (b<<15) + cg*16)
#pragma unroll
  for (int it = 0; it < 2; ++it) {
    int ln = wave + 8 * it + 4 * sub;   // 0..15, bijective
    if (l < 30) {
      int v = vbase + ln;
      int t0 = l, t1 = 30 + l;
      int idx0 = (t0 >> 2) * 512 + ((t0 & 3) * 16 + ln) * 8;
      int idx1 = (t1 >> 2) * 512 + ((t1 & 3) * 16 + ln) * 8;
      int n = cnt[v];
      if (n == 0) {
        u8pack z;
#pragma unroll
        for (int j = 0; j < 8; j++) z.u[j] = 0;
        *(short8v*)&sh[idx0] = z.v;
        *(short8v*)&sh[idx1] = z.v;
      } else {
        int start = offs[v] - n;
        const int* sp = sorted + (b << 15) + start;
        float mx[8], mn[8];
#pragma unroll
        for (int j = 0; j < 8; j++) { mx[j] = -__builtin_inff(); mn[j] = __builtin_inff(); }
        int j = 0;
        for (; j + 2 <= n; j += 2) {
          int r0 = sp[j], r1 = sp[j + 1];
          u8pack u0, u1;
          u0.v = *(const short8v*)(ft + (size_t)r0 * CH + l * 8);
          u1.v = *(const short8v*)(ft + (size_t)r1 * CH + l * 8);
#pragma unroll
          for (int k = 0; k < 8; k++) {
            float a = bf2f(u0.u[k]), c = bf2f(u1.u[k]);
            mx[k] = fmaxf(mx[k], fmaxf(a, c));
            mn[k] = fminf(mn[k], fminf(a, c));
          }
        }
        if (j < n) {
          int r0 = sp[j];
          u8pack u0;
          u0.v = *(const short8v*)(ft + (size_t)r0 * CH + l * 8);
#pragma unroll
          for (int k = 0; k < 8; k++) {
            float a = bf2f(u0.u[k]);
            mx[k] = fmaxf(mx[k], a);
            mn[k] = fminf(mn[k], a);
          }
        }
        u8pack omx, omn;
#pragma unroll
        for (int k = 0; k < 8; k++) { omx.u[k] = f2bf(mx[k]); omn.u[k] = f2bf(mn[k]); }
        *(short8v*)&sh[idx0] = omx.v;
        *(short8v*)&sh[idx1] = omn.v;
      }
    }
  }
  __syncthreads();
  unsigned short* dst = feaf + (size_t)bcg * 7680;
  for (int i = threadIdx.x; i < 960; i += 256)
    *(int4*)&dst[i * 8] = *(const int4*)&sh[i * 8];
}

// ---------------- GEMM: per-kc double-buffered LDS w (global_load_lds), static unroll ------
// 256 thr, 2 blocks/CU -> 2 waves/SIMD, 256 regs/wave. acc 120 + b 16 + misc fits.
__global__ __launch_bounds__(256, 2) void k_gemm5(const unsigned short* __restrict__ wfrag,
                                                  const unsigned short* __restrict__ feaf,
                                                  const float* __restrict__ bias,
                                                  float* __restrict__ out,
                                                  float* __restrict__ gstats) {
  __shared__ unsigned short wl0[7680];   // 15,360 B buffer A (one kc of w frags)
  __shared__ unsigned short wl1[7680];   // 15,360 B buffer B
  __shared__ float bstats[2 * CH];
  for (int i = threadIdx.x; i < 2 * CH; i += 256) bstats[i] = 0.0f;

  int bz = blockIdx.z;
  int wave = threadIdx.x >> 6, lane = threadIdx.x & 63;
  int ln = lane & 15, q = lane >> 4;
  int v0 = blockIdx.x * 128 + wave * 32;
  int cg0 = v0 >> 4;

  float4v acc[15][2];
#pragma unroll
  for (int m = 0; m < 15; m++) {
    acc[m][0] = (float4v){0.f, 0.f, 0.f, 0.f};
    acc[m][1] = (float4v){0.f, 0.f, 0.f, 0.f};
  }

  // b0: cols v0+ln (cg0), b1: cols v0+16+ln (cg0+1); contiguous 1KB per wave-load
  const unsigned short* fb = feaf + ((size_t)(bz * 2048 + cg0) * 15) * 512 + lane * 8;

  short8v bc0, bc1, bn0, bn1;
  // prologue: stage kc=0 into wl0 (async), prefetch b frags for kc=0
  {
    const unsigned short* gs = wfrag + lane * 8;
    for (int i = wave; i < 15; i += 4) gl_lds16(gs + i * 512, wl0 + i * 512);
    bc0 = *(const short8v*)(fb);
    bc1 = *(const short8v*)(fb + (size_t)15 * 512);
  }

#pragma unroll
  for (int kc = 0; kc < 15; ++kc) {
    __syncthreads();   // staged kc ready; prev compute done before restaging its buffer
    if (kc < 14) {
      unsigned short* dstb = ((kc + 1) & 1) ? wl1 : wl0;
      const unsigned short* gs = wfrag + (size_t)(kc + 1) * 7680 + lane * 8;
      for (int i = wave; i < 15; i += 4) gl_lds16(gs + i * 512, dstb + i * 512);
      bn0 = *(const short8v*)(fb + (size_t)(kc + 1) * 512);
      bn1 = *(const short8v*)(fb + (size_t)(15 + kc + 1) * 512);
    }
    const unsigned short* wb = (kc & 1) ? wl1 : wl0;
    const unsigned short* wp = wb + lane * 8;
#pragma unroll
    for (int m = 0; m < 15; ++m) {
      short8v a = *(const short8v*)(wp + m * 512);
      acc[m][0] = __builtin_amdgcn_mfma_f32_16x16x32_bf16(a, bc0, acc[m][0], 0, 0, 0);
      acc[m][1] = __builtin_amdgcn_mfma_f32_16x16x32_bf16(a, bc1, acc[m][1], 0, 0, 0);
    }
    bc0 = bn0; bc1 = bn1;
  }

  // epilogue: y = acc + bias; store; per-channel sum/sumsq reduction
  float* o0 = out + (size_t)bz * CH * R3 + v0 + ln;
  float* o1 = o0 + 16;
#pragma unroll
  for (int m = 0; m < 15; ++m) {
    int cbase = m * 16 + q * 4;
    float s[4], sq[4];
#pragma unroll
    for (int r = 0; r < 4; ++r) {
      float bb = bias[cbase + r];
      float y0 = acc[m][0][r] + bb;
      float y1 = acc[m][1][r] + bb;
      o0[(size_t)(cbase + r) * R3] = y0;
      o1[(size_t)(cbase + r) * R3] = y1;
      s[r] = y0 + y1;
      sq[r] = y0 * y0 + y1 * y1;
    }
#pragma unroll
    for (int off = 1; off < 16; off <<= 1) {
#pragma unroll
      for (int r = 0; r < 4; ++r) {
        s[r] += __shfl_xor(s[r], off);
        sq[r] += __shfl_xor(sq[r], off);
      }
    }
    if (ln == 0) {
#pragma unroll
      for (int r = 0; r < 4; ++r) {
        atomicAdd(&bstats[cbase + r], s[r]);
        atomicAdd(&bstats[CH + cbase + r], sq[r]);
      }
    }
  }
  __syncthreads();
  for (int i = threadIdx.x; i < 2 * CH; i += 256) atomicAdd(&gstats[i], bstats[i]);
}

// ---------------- apply BN (stats->scale inline) + swish in place ----------------
__global__ void k_apply(float* __restrict__ y, const float* __restrict__ stats,
                        const float* __restrict__ gamma, const float* __restrict__ beta) {
  int g = blockIdx.x * 256 + threadIdx.x;  // float4 chunk id
  int c = (g >> 13) % CH;                  // 8192 chunks per (b,c) row
  const float ninv = 1.0f / (float)(NB * R3);
  float mean = stats[c] * ninv;
  float var = stats[CH + c] * ninv - mean * mean;
  float s = gamma[c] * rsqrtf(var + 1e-5f);
  float h = beta[c] - mean * s;
  float4 v = ((const float4*)y)[g];
  float t0 = v.x * s + h; v.x = t0 / (1.0f + __expf(-t0));
  float t1 = v.y * s + h; v.y = t1 / (1.0f + __expf(-t1));
  float t2 = v.z * s + h; v.z = t2 / (1.0f + __expf(-t2));
  float t3 = v.w * s + h; v.w = t3 / (1.0f + __expf(-t3));
  ((float4*)y)[g] = v;
}

extern "C" void kernel_launch(void* const* d_in, const int* in_sizes, int n_in,
                              void* d_out, int out_size, void* d_ws, size_t ws_size,
                              hipStream_t stream) {
  const float* features = (const float*)d_in[0];
  const float* coords   = (const float*)d_in[1];
  const float* w        = (const float*)d_in[2];
  const float* bias     = (const float*)d_in[3];
  const float* gamma    = (const float*)d_in[4];
  const float* beta     = (const float*)d_in[5];
  float* out = (float*)d_out;

  char* ws = (char*)d_ws;
  size_t off = 0;
  float* ms    = (float*)(ws + off); off += 256;
  float* stats = (float*)(ws + off); off += 4096;
  int* pos     = (int*)(ws + off);   off += (size_t)NB * NPT * 4;
  int* cnt     = (int*)(ws + off);   off += (size_t)NB * R3 * 4;
  int* offs    = (int*)(ws + off);   off += (size_t)NB * R3 * 4;
  int* sorted  = (int*)(ws + off);   off += (size_t)NB * NPT * 4;
  unsigned short* wfrag = (unsigned short*)(ws + off); off += (size_t)CH * CH2 * 2;
  unsigned short* ft    = (unsigned short*)(ws + off); off += (size_t)NB * NPT * CH * 2;
  unsigned short* feaf  = (unsigned short*)(ws + off); off += (size_t)NB * R3 * CH2 * 2;

  float* ncout = out + Y_ELEMS;

  k_init<<<516, 256, 0, stream>>>(cnt, stats, w, wfrag);
  k_coord_stats<<<4, 1024, 0, stream>>>(coords, ms);
  k_pos_nc<<<512, 256, 0, stream>>>(coords, ms, ncout, pos, cnt);
  k_scan<<<4, 1024, 0, stream>>>(cnt, offs);
  k_scatter<<<512, 256, 0, stream>>>(pos, offs, sorted);
  k_transpose3<<<dim3(512, 4), 256, 0, stream>>>(features, ft);
  k_voxel4<<<NB * 2048, 256, 0, stream>>>(cnt, offs, sorted, ft, feaf);
  k_gemm5<<<dim3(256, 1, NB), 256, 0, stream>>>(wfrag, feaf, bias, out, stats);
  k_apply<<<Y_ELEMS / 1024, 256, 0, stream>>>(out, stats, gamma, beta);
}

// Round 6
// 399.773 us; speedup vs baseline: 1.6440x; 1.0548x over previous
//
#include <hip/hip_runtime.h>
#include <cstdint>
#include <cstddef>

#define RR 32
#define R3 32768
#define NPT 32768
#define CH 240
#define CH2 480
#define NB 4
#define Y_ELEMS 31457280   // 4*240*32768

typedef __attribute__((ext_vector_type(8))) short short8v;
typedef __attribute__((ext_vector_type(4))) float float4v;

union u8pack { short8v v; unsigned short u[8]; };

static __device__ __forceinline__ float bf2f(unsigned short u) {
  return __uint_as_float(((unsigned int)u) << 16);
}
static __device__ __forceinline__ unsigned short f2bf(float f) {
  unsigned int u = __float_as_uint(f);
  u = (u + 0x7FFFu + ((u >> 16) & 1u)) >> 16;
  return (unsigned short)u;
}

// async global->LDS, 16B per lane; LDS base is wave-uniform, lane*16 added by HW
static __device__ __forceinline__ void gl_lds16(const void* g, void* l) {
  __builtin_amdgcn_global_load_lds((const __attribute__((address_space(1))) unsigned int*)g,
                                   (__attribute__((address_space(3))) unsigned int*)l, 16, 0, 0);
}

// ---------------- init: zero cnt+stats, pack w fp32 [240][480] -> bf16 frag order ----------
// wfrag ushort idx: ((mg*75 + kc*5 + mL)*64 + lane)*8 + j
//   holds w[(mg*5+mL)*16 + ln][kc*32 + q*8 + j], lane = q*16+ln
__global__ void k_init(int* __restrict__ cnt, float* __restrict__ stats,
                       const float* __restrict__ w, unsigned short* __restrict__ wfrag) {
  int g = blockIdx.x * 256 + threadIdx.x;
  if (g < NB * R3) cnt[g] = 0;
  if (g < 1024) stats[g] = 0.0f;
  if (g < 14400) {
    int lane = g & 63, t = g >> 6;      // t 0..224
    int mg = t / 75, r = t % 75;
    int kc = r / 5, mL = r % 5;
    int m = mg * 5 + mL;
    int ln = lane & 15, q = lane >> 4;
    const float* src = w + (size_t)(m * 16 + ln) * CH2 + kc * 32 + q * 8;
    u8pack pk;
#pragma unroll
    for (int j = 0; j < 8; j++) pk.u[j] = f2bf(src[j]);
    *(short8v*)&wfrag[(size_t)g * 8] = pk.v;
  }
}

// ---------------- per-batch coord mean + scale (1024 thr, float4) ----------------
__global__ __launch_bounds__(1024) void k_coord_stats(const float* __restrict__ coords,
                                                      float* __restrict__ ms) {
  __shared__ float red[1024];
  __shared__ float mean[3];
  int b = blockIdx.x, t = threadIdx.x;
  const float4* cb4 = (const float4*)(coords + (size_t)b * 3 * NPT);
  float s[3] = {0.f, 0.f, 0.f};
  for (int i = t; i < NPT / 4; i += 1024) {
#pragma unroll
    for (int d = 0; d < 3; d++) {
      float4 v = cb4[d * (NPT / 4) + i];
      s[d] += (v.x + v.y) + (v.z + v.w);
    }
  }
  for (int d = 0; d < 3; d++) {
    red[t] = s[d]; __syncthreads();
    for (int k = 512; k > 0; k >>= 1) { if (t < k) red[t] += red[t + k]; __syncthreads(); }
    if (t == 0) mean[d] = red[0] * (1.0f / NPT);
    __syncthreads();
  }
  float m0 = mean[0], m1 = mean[1], m2 = mean[2];
  float mx = 0.f;
  for (int i = t; i < NPT / 4; i += 1024) {
    float4 x = cb4[i], y = cb4[NPT / 4 + i], z = cb4[2 * (NPT / 4) + i];
    float dx, dy, dz, n;
    dx = x.x - m0; dy = y.x - m1; dz = z.x - m2; n = dx * dx + dy * dy + dz * dz; mx = fmaxf(mx, n);
    dx = x.y - m0; dy = y.y - m1; dz = z.y - m2; n = dx * dx + dy * dy + dz * dz; mx = fmaxf(mx, n);
    dx = x.z - m0; dy = y.z - m1; dz = z.z - m2; n = dx * dx + dy * dy + dz * dz; mx = fmaxf(mx, n);
    dx = x.w - m0; dy = y.w - m1; dz = z.w - m2; n = dx * dx + dy * dy + dz * dz; mx = fmaxf(mx, n);
  }
  red[t] = mx; __syncthreads();
  for (int k = 512; k > 0; k >>= 1) { if (t < k) red[t] = fmaxf(red[t], red[t + k]); __syncthreads(); }
  if (t == 0) {
    ms[b * 4 + 0] = m0; ms[b * 4 + 1] = m1; ms[b * 4 + 2] = m2;
    ms[b * 4 + 3] = sqrtf(red[0]) * 2.0f;  // EPS_NORM = 0
  }
}

// ---------------- nc output + voxel id + histogram ----------------
__global__ void k_pos_nc(const float* __restrict__ coords, const float* __restrict__ ms,
                         float* __restrict__ ncout, int* __restrict__ pos, int* __restrict__ cnt) {
  int g = blockIdx.x * 256 + threadIdx.x;  // 0 .. NB*NPT-1
  int b = g >> 15, i = g & (NPT - 1);
  const float* cb = coords + (size_t)b * 3 * NPT;
  float scale = ms[b * 4 + 3];
  int vox[3];
#pragma unroll
  for (int d = 0; d < 3; d++) {
    float v = (cb[(size_t)d * NPT + i] - ms[b * 4 + d]) / scale + 0.5f;
    v = fminf(fmaxf(v * (float)RR, 0.0f), (float)(RR - 1));
    ncout[((size_t)(b * 3 + d)) * NPT + i] = v;
    vox[d] = (int)rintf(v);  // round-half-even, matches jnp.round
  }
  int p = (b << 15) | (vox[0] + (vox[1] << 5) + (vox[2] << 10));
  pos[g] = p;
  atomicAdd(&cnt[p], 1);
}

// ---------------- exclusive scan per batch (32768 entries) ----------------
__global__ void k_scan(const int* __restrict__ cnt, int* __restrict__ offs) {
  __shared__ int part[1024];
  int b = blockIdx.x, t = threadIdx.x;
  const int base = b * R3;
  int local[32];
  int s = 0;
#pragma unroll
  for (int j = 0; j < 32; j++) { local[j] = cnt[base + t * 32 + j]; s += local[j]; }
  part[t] = s; __syncthreads();
  for (int d = 1; d < 1024; d <<= 1) {
    int v = (t >= d) ? part[t - d] : 0;
    __syncthreads();
    part[t] += v;
    __syncthreads();
  }
  int run = (t == 0) ? 0 : part[t - 1];
#pragma unroll
  for (int j = 0; j < 32; j++) { offs[base + t * 32 + j] = run; run += local[j]; }
}

// ---------------- scatter global point ids into voxel-sorted order ----------------
__global__ void k_scatter(const int* __restrict__ pos, int* __restrict__ offs,
                          int* __restrict__ sorted) {
  int g = blockIdx.x * 256 + threadIdx.x;
  int p = pos[g];
  int slot = atomicAdd(&offs[p], 1);  // offs becomes "end" after this kernel
  sorted[((g >> 15) << 15) + slot] = g;  // g = global point row id into ft
}

// ---------------- transpose features [B,C,N] fp32 -> ft[point][240] bf16, coalesced -----
__global__ void k_transpose3(const float* __restrict__ f, unsigned short* __restrict__ ft) {
  __shared__ float tile[CH * 65];  // 62,400 B
  int p0 = blockIdx.x * 64, b = blockIdx.y;
  int t = threadIdx.x;
  {
    int pp = t & 63, cq = t >> 6;  // cq 0..3
    const float* src = f + ((size_t)b * CH) * NPT + p0 + pp;
#pragma unroll 4
    for (int j = 0; j < 60; ++j) {
      int c = j * 4 + cq;
      tile[c * 65 + pp] = src[(size_t)c * NPT];
    }
  }
  __syncthreads();
  int ch8 = t & 7;
#pragma unroll
  for (int pass = 0; pass < 2; ++pass) {
    int p = pass * 32 + (t >> 3);
    unsigned short* dst = ft + ((size_t)(b * NPT + p0 + p)) * CH;
#pragma unroll
    for (int i = 0; i < 4; ++i) {
      int ch = ch8 + 8 * i;          // 16-byte chunk id, 0..29 valid
      if (ch < 30) {
        u8pack pk;
#pragma unroll
        for (int jj = 0; jj < 8; ++jj) pk.u[jj] = f2bf(tile[(ch * 8 + jj) * 65 + p]);
        *(short8v*)&dst[ch * 8] = pk.v;
      }
    }
  }
}

// ---------------- per-voxel max/min gather -> LDS cg-image -> coalesced feaf ----------------
// feaf layout ushort idx: ((b*2048+cg)*15 + kc)*512 + (q*16+ln)*8 + j
__global__ __launch_bounds__(256) void k_voxel4(const int* __restrict__ cnt,
                                                const int* __restrict__ offs,
                                                const int* __restrict__ sorted,
                                                const unsigned short* __restrict__ ft,
                                                unsigned short* __restrict__ feaf) {
  __shared__ unsigned short sh[7680];   // 15,360 B: exact feaf image of this cg
  int bcg = blockIdx.x;                 // b*2048 + cg
  int b = bcg >> 11;
  int wave = threadIdx.x >> 6, lane = threadIdx.x & 63;
  int sub = lane >> 5, l = lane & 31;
  int vbase = bcg << 4;                 // global voxel id base
#pragma unroll
  for (int it = 0; it < 2; ++it) {
    int ln = wave + 8 * it + 4 * sub;   // 0..15, bijective
    if (l < 30) {
      int v = vbase + ln;
      int t0 = l, t1 = 30 + l;
      int idx0 = (t0 >> 2) * 512 + ((t0 & 3) * 16 + ln) * 8;
      int idx1 = (t1 >> 2) * 512 + ((t1 & 3) * 16 + ln) * 8;
      int n = cnt[v];
      if (n == 0) {
        u8pack z;
#pragma unroll
        for (int j = 0; j < 8; j++) z.u[j] = 0;
        *(short8v*)&sh[idx0] = z.v;
        *(short8v*)&sh[idx1] = z.v;
      } else {
        int start = offs[v] - n;
        const int* sp = sorted + (b << 15) + start;
        float mx[8], mn[8];
#pragma unroll
        for (int j = 0; j < 8; j++) { mx[j] = -__builtin_inff(); mn[j] = __builtin_inff(); }
        int j = 0;
        for (; j + 2 <= n; j += 2) {
          int r0 = sp[j], r1 = sp[j + 1];
          u8pack u0, u1;
          u0.v = *(const short8v*)(ft + (size_t)r0 * CH + l * 8);
          u1.v = *(const short8v*)(ft + (size_t)r1 * CH + l * 8);
#pragma unroll
          for (int k = 0; k < 8; k++) {
            float a = bf2f(u0.u[k]), c = bf2f(u1.u[k]);
            mx[k] = fmaxf(mx[k], fmaxf(a, c));
            mn[k] = fminf(mn[k], fminf(a, c));
          }
        }
        if (j < n) {
          int r0 = sp[j];
          u8pack u0;
          u0.v = *(const short8v*)(ft + (size_t)r0 * CH + l * 8);
#pragma unroll
          for (int k = 0; k < 8; k++) {
            float a = bf2f(u0.u[k]);
            mx[k] = fmaxf(mx[k], a);
            mn[k] = fminf(mn[k], a);
          }
        }
        u8pack omx, omn;
#pragma unroll
        for (int k = 0; k < 8; k++) { omx.u[k] = f2bf(mx[k]); omn.u[k] = f2bf(mn[k]); }
        *(short8v*)&sh[idx0] = omx.v;
        *(short8v*)&sh[idx1] = omn.v;
      }
    }
  }
  __syncthreads();
  unsigned short* dst = feaf + (size_t)bcg * 7680;
  for (int i = threadIdx.x; i < 960; i += 256)
    *(int4*)&dst[i * 8] = *(const int4*)&sh[i * 8];
}

// ---------------- GEMM m-split: stage 5 m-tiles of w ONCE, no main-loop barriers ----------
// block = 256 thr (4 waves), grid (128 colblk, 3 mg, NB). Wave: n=64 cols, acc[5][4]=80 AGPR.
// LDS 76.8KB w-slice + bstats -> 2 blocks/CU, 256 regs/wave.
__global__ __launch_bounds__(256, 2) void k_gemm6(const unsigned short* __restrict__ wfrag,
                                                  const unsigned short* __restrict__ feaf,
                                                  const float* __restrict__ bias,
                                                  unsigned short* __restrict__ ybf,
                                                  float* __restrict__ gstats) {
  __shared__ unsigned short wl[75 * 512];   // 76,800 B: this mg's w frags, [kc*5+mL][lane*8]
  __shared__ float bstats[160];             // 80 sum + 80 sumsq (this mg's channels)
  int wave = threadIdx.x >> 6, lane = threadIdx.x & 63;
  int ln = lane & 15, q = lane >> 4;
  int mg = blockIdx.y, bz = blockIdx.z;

  for (int i = threadIdx.x; i < 160; i += 256) bstats[i] = 0.0f;

  // stage w slice (once)
  {
    const unsigned short* gs = wfrag + (size_t)mg * 75 * 512 + lane * 8;
    for (int i = wave; i < 75; i += 4) gl_lds16(gs + i * 512, wl + i * 512);
  }

  int v0 = blockIdx.x * 256 + wave * 64;
  int cg0 = v0 >> 4;
  const unsigned short* fbb = feaf + ((size_t)(bz * 2048 + cg0) * 15) * 512 + lane * 8;

  float4v acc[5][4];
#pragma unroll
  for (int m = 0; m < 5; m++)
#pragma unroll
    for (int j = 0; j < 4; j++) acc[m][j] = (float4v){0.f, 0.f, 0.f, 0.f};

  short8v cb0 = *(const short8v*)(fbb + (size_t)(0 * 15 + 0) * 512);
  short8v cb1 = *(const short8v*)(fbb + (size_t)(1 * 15 + 0) * 512);
  short8v cb2 = *(const short8v*)(fbb + (size_t)(2 * 15 + 0) * 512);
  short8v cb3 = *(const short8v*)(fbb + (size_t)(3 * 15 + 0) * 512);

  __syncthreads();  // w slice staged (also covers bstats init)

#pragma unroll
  for (int kc = 0; kc < 15; ++kc) {
    short8v nb0, nb1, nb2, nb3;
    if (kc < 14) {
      nb0 = *(const short8v*)(fbb + (size_t)(0 * 15 + kc + 1) * 512);
      nb1 = *(const short8v*)(fbb + (size_t)(1 * 15 + kc + 1) * 512);
      nb2 = *(const short8v*)(fbb + (size_t)(2 * 15 + kc + 1) * 512);
      nb3 = *(const short8v*)(fbb + (size_t)(3 * 15 + kc + 1) * 512);
    }
    const unsigned short* wp = wl + (size_t)(kc * 5) * 512 + lane * 8;
#pragma unroll
    for (int mL = 0; mL < 5; ++mL) {
      short8v a = *(const short8v*)(wp + (size_t)mL * 512);
      acc[mL][0] = __builtin_amdgcn_mfma_f32_16x16x32_bf16(a, cb0, acc[mL][0], 0, 0, 0);
      acc[mL][1] = __builtin_amdgcn_mfma_f32_16x16x32_bf16(a, cb1, acc[mL][1], 0, 0, 0);
      acc[mL][2] = __builtin_amdgcn_mfma_f32_16x16x32_bf16(a, cb2, acc[mL][2], 0, 0, 0);
      acc[mL][3] = __builtin_amdgcn_mfma_f32_16x16x32_bf16(a, cb3, acc[mL][3], 0, 0, 0);
    }
    if (kc < 14) { cb0 = nb0; cb1 = nb1; cb2 = nb2; cb3 = nb3; }
  }

  // epilogue: y = acc + bias -> bf16 store; per-channel sum/sumsq
  unsigned short* yb = ybf + ((size_t)bz * CH) * R3 + v0 + ln;
#pragma unroll
  for (int mL = 0; mL < 5; ++mL) {
#pragma unroll
    for (int r = 0; r < 4; ++r) {
      int cl = mL * 16 + q * 4 + r;    // channel local to mg
      int c = mg * 80 + cl;
      float bb = bias[c];
      float y0 = acc[mL][0][r] + bb;
      float y1 = acc[mL][1][r] + bb;
      float y2 = acc[mL][2][r] + bb;
      float y3 = acc[mL][3][r] + bb;
      unsigned short* yrow = yb + (size_t)c * R3;
      yrow[0] = f2bf(y0); yrow[16] = f2bf(y1); yrow[32] = f2bf(y2); yrow[48] = f2bf(y3);
      float s = (y0 + y1) + (y2 + y3);
      float sq = (y0 * y0 + y1 * y1) + (y2 * y2 + y3 * y3);
#pragma unroll
      for (int off = 1; off < 16; off <<= 1) {
        s += __shfl_xor(s, off);
        sq += __shfl_xor(sq, off);
      }
      if (ln == 0) {
        atomicAdd(&bstats[cl], s);
        atomicAdd(&bstats[80 + cl], sq);
      }
    }
  }
  __syncthreads();
  for (int i = threadIdx.x; i < 160; i += 256) {
    int g = (i < 80) ? (mg * 80 + i) : (CH + mg * 80 + (i - 80));
    atomicAdd(&gstats[g], bstats[i]);
  }
}

// ---------------- apply BN (stats->scale inline) + swish: ybf bf16 -> out fp32 ----------
__global__ void k_apply(const unsigned short* __restrict__ ybf, float* __restrict__ out,
                        const float* __restrict__ stats, const float* __restrict__ gamma,
                        const float* __restrict__ beta) {
  int g = blockIdx.x * 256 + threadIdx.x;  // 8-elem chunk id; 4096 chunks per (b,c) row
  int c = (g >> 12) % CH;
  const float ninv = 1.0f / (float)(NB * R3);
  float mean = stats[c] * ninv;
  float var = stats[CH + c] * ninv - mean * mean;
  float s = gamma[c] * rsqrtf(var + 1e-5f);
  float h = beta[c] - mean * s;
  u8pack v;
  v.v = *(const short8v*)(ybf + (size_t)g * 8);
  float4 o0, o1;
  float t;
  t = bf2f(v.u[0]) * s + h; o0.x = t / (1.0f + __expf(-t));
  t = bf2f(v.u[1]) * s + h; o0.y = t / (1.0f + __expf(-t));
  t = bf2f(v.u[2]) * s + h; o0.z = t / (1.0f + __expf(-t));
  t = bf2f(v.u[3]) * s + h; o0.w = t / (1.0f + __expf(-t));
  t = bf2f(v.u[4]) * s + h; o1.x = t / (1.0f + __expf(-t));
  t = bf2f(v.u[5]) * s + h; o1.y = t / (1.0f + __expf(-t));
  t = bf2f(v.u[6]) * s + h; o1.z = t / (1.0f + __expf(-t));
  t = bf2f(v.u[7]) * s + h; o1.w = t / (1.0f + __expf(-t));
  ((float4*)out)[(size_t)g * 2] = o0;
  ((float4*)out)[(size_t)g * 2 + 1] = o1;
}

extern "C" void kernel_launch(void* const* d_in, const int* in_sizes, int n_in,
                              void* d_out, int out_size, void* d_ws, size_t ws_size,
                              hipStream_t stream) {
  const float* features = (const float*)d_in[0];
  const float* coords   = (const float*)d_in[1];
  const float* w        = (const float*)d_in[2];
  const float* bias     = (const float*)d_in[3];
  const float* gamma    = (const float*)d_in[4];
  const float* beta     = (const float*)d_in[5];
  float* out = (float*)d_out;

  char* ws = (char*)d_ws;
  size_t off = 0;
  float* ms    = (float*)(ws + off); off += 256;
  float* stats = (float*)(ws + off); off += 4096;
  int* pos     = (int*)(ws + off);   off += (size_t)NB * NPT * 4;
  int* cnt     = (int*)(ws + off);   off += (size_t)NB * R3 * 4;
  int* offs    = (int*)(ws + off);   off += (size_t)NB * R3 * 4;
  int* sorted  = (int*)(ws + off);   off += (size_t)NB * NPT * 4;
  unsigned short* wfrag = (unsigned short*)(ws + off); off += (size_t)CH * CH2 * 2;
  unsigned short* ft    = (unsigned short*)(ws + off); off += (size_t)NB * NPT * CH * 2;
  unsigned short* feaf  = (unsigned short*)(ws + off); off += (size_t)NB * R3 * CH2 * 2;
  unsigned short* ybf   = ft;  // ft is dead after k_voxel4; same size (63 MB)

  float* ncout = out + Y_ELEMS;

  k_init<<<516, 256, 0, stream>>>(cnt, stats, w, wfrag);
  k_coord_stats<<<4, 1024, 0, stream>>>(coords, ms);
  k_pos_nc<<<512, 256, 0, stream>>>(coords, ms, ncout, pos, cnt);
  k_scan<<<4, 1024, 0, stream>>>(cnt, offs);
  k_scatter<<<512, 256, 0, stream>>>(pos, offs, sorted);
  k_transpose3<<<dim3(512, 4), 256, 0, stream>>>(features, ft);
  k_voxel4<<<NB * 2048, 256, 0, stream>>>(cnt, offs, sorted, ft, feaf);
  k_gemm6<<<dim3(128, 3, NB), 256, 0, stream>>>(wfrag, feaf, bias, ybf, stats);
  k_apply<<<Y_ELEMS / 2048, 256, 0, stream>>>(ybf, out, stats, gamma, beta);
}